// Round 12
// baseline (365.326 us; speedup 1.0000x reference)
//
#include <hip/hip_runtime.h>
#include <hip/hip_bf16.h>

typedef __attribute__((ext_vector_type(4))) float f32x4;
typedef __attribute__((ext_vector_type(8))) short bf16x8;
typedef unsigned short u16;
typedef unsigned int u32;
typedef __attribute__((ext_vector_type(4))) u16 u16x4;

#define DEV static __device__ __forceinline__

constexpr int Bb = 2, Ss = 2048, Dd = 1024, Hh = 16, DKk = 64;
constexpr int Mm = Bb * Ss;   // 4096 token rows

DEV float bf2f(u16 u) { union { u32 i; float f; } v; v.i = (u32)u << 16; return v.f; }
DEV u16 f2bf(float f) {
  union { float f; u32 i; } v; v.f = f;
  u32 r = v.i + 0x7FFFu + ((v.i >> 16) & 1u);
  return (u16)(r >> 16);
}

DEV void gload_lds16(const u16* g, u16* l) {
  __builtin_amdgcn_global_load_lds((const __attribute__((address_space(1))) u32*)g,
                                   (__attribute__((address_space(3))) u32*)l, 16, 0, 0);
}

// byte-offset swizzle within a 16KB half-tile [128 rows][128B] (involution)
DEV int swz16(int o) {
  return o ^ (((o >> 8) & 1) << 6) ^ (((o >> 9) & 1) << 5);
}

// ---------------- merged: weight convert + rmsnorm1 + rope table ----------------
// w13 layout: interleaved 16-row groups (see R11). rope table: [s][p] cos/sin.
__global__ __launch_bounds__(256) void k_prep(const float* __restrict__ wq, const float* __restrict__ wk,
                          const float* __restrict__ wv, const float* __restrict__ wo,
                          const float* __restrict__ w1, const float* __restrict__ w2,
                          const float* __restrict__ w3,
                          u16* __restrict__ wqkv, u16* __restrict__ wob,
                          u16* __restrict__ w13, u16* __restrict__ w2b,
                          const float* __restrict__ x, const float* __restrict__ ln1,
                          u16* __restrict__ xn, const int* __restrict__ tp,
                          float* __restrict__ ctab, float* __restrict__ stab) {
  if (blockIdx.x < 16384) {
    int i = (blockIdx.x * 256 + threadIdx.x) * 4;
    int seg = i >> 20;
    const float* src; u16* dst;
    if (seg == 0)      { src = wq + i;             dst = wqkv + i; }
    else if (seg == 1) { src = wk + (i - (1<<20)); dst = wqkv + i; }
    else if (seg == 2) { src = wv + (i - (2<<20)); dst = wqkv + i; }
    else if (seg == 3) { src = wo + (i - (3<<20)); dst = wob  + (i - (3<<20)); }
    else if (seg < 8)  {
      int ii = i - (4<<20);
      int ri = ii >> 10, ci = ii & 1023;
      int dr = ((ri >> 4) << 5) + (ri & 15);
      src = w1 + ii; dst = w13 + (long)dr * 1024 + ci;
    }
    else if (seg < 12) { src = w2 + (i - (8<<20)); dst = w2b  + (i - (8<<20)); }
    else {
      int ii = i - (12<<20);
      int ri = ii >> 10, ci = ii & 1023;
      int dr = ((ri >> 4) << 5) + 16 + (ri & 15);
      src = w3 + ii; dst = w13 + (long)dr * 1024 + ci;
    }
    float4 v = *(const float4*)src;
    u16x4 o = { f2bf(v.x), f2bf(v.y), f2bf(v.z), f2bf(v.w) };
    *(u16x4*)dst = o;
  } else if (blockIdx.x < 16384 + Mm) {
    int row = blockIdx.x - 16384;
    int t = threadIdx.x;
    float4 v = ((const float4*)(x + (long)row * Dd))[t];
    float ss = v.x * v.x + v.y * v.y + v.z * v.z + v.w * v.w;
#pragma unroll
    for (int m = 32; m; m >>= 1) ss += __shfl_xor(ss, m, 64);
    __shared__ float red[4];
    if ((t & 63) == 0) red[t >> 6] = ss;
    __syncthreads();
    float tot = red[0] + red[1] + red[2] + red[3];
    float r = rsqrtf(tot * (1.0f / Dd) + 1e-5f);
    float4 wv2 = ((const float4*)ln1)[t];
    u16x4 o = { f2bf(v.x * r * wv2.x), f2bf(v.y * r * wv2.y),
                f2bf(v.z * r * wv2.z), f2bf(v.w * r * wv2.w) };
    ((u16x4*)(xn + (long)row * Dd))[t] = o;
  } else {
    int e = (blockIdx.x - 16384 - Mm) * 256 + threadIdx.x;   // 0..65535
    int srow = e >> 5, p = e & 31;
    float pos = (float)tp[srow];
    float invf = __expf(-(float)p * (2.0f / DKk) * 9.2103403719761836f);
    float fr = pos * invf;
    float sn, cs;
    sincosf(fr, &sn, &cs);
    ctab[e] = cs;
    stab[e] = sn;
  }
}

// ---------------- RMSNorm ----------------
__global__ __launch_bounds__(256) void k_rmsnorm(const float* __restrict__ x,
                                                 const float* __restrict__ w,
                                                 u16* __restrict__ out) {
  int row = blockIdx.x;
  int t = threadIdx.x;
  float4 v = ((const float4*)(x + (long)row * Dd))[t];
  float ss = v.x * v.x + v.y * v.y + v.z * v.z + v.w * v.w;
#pragma unroll
  for (int m = 32; m; m >>= 1) ss += __shfl_xor(ss, m, 64);
  __shared__ float red[4];
  if ((t & 63) == 0) red[t >> 6] = ss;
  __syncthreads();
  float tot = red[0] + red[1] + red[2] + red[3];
  float r = rsqrtf(tot * (1.0f / Dd) + 1e-5f);
  float4 wv = ((const float4*)w)[t];
  u16x4 o = { f2bf(v.x * r * wv.x), f2bf(v.y * r * wv.y),
              f2bf(v.z * r * wv.z), f2bf(v.w * r * wv.w) };
  ((u16x4*)(out + (long)row * Dd))[t] = o;
}

// ---------------- final reduce: out = sum(4 bf16 partials) + x2 ----------------
__global__ void k_addout4(const u16* __restrict__ p, const float* __restrict__ x2,
                          float* __restrict__ out) {
  int i = (blockIdx.x * 256 + threadIdx.x) * 4;
  float4 c = *(const float4*)(x2 + i);
  float s0 = c.x, s1 = c.y, s2 = c.z, s3 = c.w;
#pragma unroll
  for (int z = 0; z < 4; z++) {
    u16x4 a = *(const u16x4*)(p + (long)z * Mm * 1024 + i);
    s0 += bf2f(a[0]); s1 += bf2f(a[1]); s2 += bf2f(a[2]); s3 += bf2f(a[3]);
  }
  float4 o = { s0, s1, s2, s3 };
  *(float4*)(out + i) = o;
}

// ---------------- m97-style 128x128 NT GEMM (WO) ----------------
template <int OM, bool RES>
__global__ __launch_bounds__(256) void k_gemm(const u16* __restrict__ A,
                                              const u16* __restrict__ Bm,
                                              void* __restrict__ Cout,
                                              const float* __restrict__ Rres,
                                              int N, int Kl, int Kstr) {
  __shared__ u16 Abuf[128 * 32];
  __shared__ u16 Bbuf[128 * 32];
  const int tid = threadIdx.x;
  const int wid = tid >> 6, lane = tid & 63;
  const int wm = wid >> 1, wn = wid & 1;
  const int lq = lane >> 4, ll = lane & 15;
  const int lin = blockIdx.y * gridDim.x + blockIdx.x;
  const int c = lin & 7, j = lin >> 3;
  const int ncc = gridDim.x >> 2;
  const int bxc = (c % ncc) * 4 + (j & 3);
  const int byc = (c / ncc) * 8 + (j >> 2);
  const int m0 = byc * 128, n0 = bxc * 128;

  const u16* Ap = A + (long)blockIdx.z * Kl;
  const u16* Bp = Bm + (long)blockIdx.z * Kl;

  f32x4 acc[4][4] = {};

  const int srow = tid >> 2;
  const int scol = (tid & 3) * 8;
  const long aoff = (long)(m0 + srow) * Kstr + scol;
  const long boff = (long)(n0 + srow) * Kstr + scol;
  u16* aldsw = Abuf + wid * 512;
  u16* bldsw = Bbuf + wid * 512;

  for (int k0 = 0; k0 < Kl; k0 += 32) {
    __syncthreads();
    gload_lds16(Ap + aoff + k0, aldsw);
    gload_lds16(Ap + aoff + (long)64 * Kstr + k0, aldsw + 2048);
    gload_lds16(Bp + boff + k0, bldsw);
    gload_lds16(Bp + boff + (long)64 * Kstr + k0, bldsw + 2048);
    __syncthreads();
    bf16x8 af[4], bfr[4];
#pragma unroll
    for (int i = 0; i < 4; i++)
      af[i] = *(const bf16x8*)&Abuf[(wm * 64 + i * 16 + ll) * 32 + lq * 8];
#pragma unroll
    for (int j2 = 0; j2 < 4; j2++)
      bfr[j2] = *(const bf16x8*)&Bbuf[(wn * 64 + j2 * 16 + ll) * 32 + lq * 8];
#pragma unroll
    for (int i = 0; i < 4; i++)
#pragma unroll
      for (int j2 = 0; j2 < 4; j2++)
        acc[i][j2] = __builtin_amdgcn_mfma_f32_16x16x32_bf16(af[i], bfr[j2], acc[i][j2], 0, 0, 0);
  }

  float* fout = (float*)Cout + (long)blockIdx.z * Mm * (long)N;
#pragma unroll
  for (int i = 0; i < 4; i++) {
    const int rowb = m0 + wm * 64 + i * 16 + lq * 4;
#pragma unroll
    for (int j2 = 0; j2 < 4; j2++) {
      const int col = n0 + wn * 64 + j2 * 16 + ll;
#pragma unroll
      for (int r = 0; r < 4; r++) {
        int rr = rowb + r;
        float v = acc[i][j2][r];
        if (RES) v += Rres[(long)rr * N + col];
        if (OM == 1) {
          fout[(long)rr * N + col] = v;
        } else {
          ((u16*)Cout)[(long)rr * N + col] = f2bf(v);
        }
      }
    }
  }
}

// ---------------- 256x256 8-phase GEMM (m201 template) ----------------
// OM: 3 = fused qkv + rope epilogue; 6 = split-K bf16 partial; 7 = W13+SwiGLU
#define STG_A(d, h, kt)                                                         \
  { gload_lds16(A + aoff[0] + (long)(h) * 128 * Kstr + (kt) * 64, &sA[d][h][dst0]); \
    gload_lds16(A + aoff[1] + (long)(h) * 128 * Kstr + (kt) * 64, &sA[d][h][dst1]); }
#define STG_B(d, h, kt)                                                         \
  { gload_lds16(Bm + boff[0] + (long)(h) * 128 * Kstr + (kt) * 64, &sB[d][h][dst0]); \
    gload_lds16(Bm + boff[1] + (long)(h) * 128 * Kstr + (kt) * 64, &sB[d][h][dst1]); }

#define PHASE(q, d, DOB, WVN, ...)                                              \
  {                                                                             \
    bf16x8 af_[2][2];                                                           \
    _Pragma("unroll") for (int s_ = 0; s_ < 2; s_++)                            \
    _Pragma("unroll") for (int kk_ = 0; kk_ < 2; kk_++) {                       \
      int ms_ = (q) * 4 + wm * 2 + s_;                                          \
      int lo_ = ((ms_ & 7) * 16 + ll) * 128 + kk_ * 64 + lq * 16;               \
      af_[s_][kk_] = *(const bf16x8*)((const char*)sA[d][ms_ >> 3] + swz16(lo_)); \
    }                                                                           \
    if (DOB) {                                                                  \
      _Pragma("unroll") for (int ns_ = 0; ns_ < 4; ns_++)                       \
      _Pragma("unroll") for (int kk_ = 0; kk_ < 2; kk_++) {                     \
        int rl_ = wn * 64 + ns_ * 16 + ll;                                      \
        int lo_ = (rl_ & 127) * 128 + kk_ * 64 + lq * 16;                       \
        bfr[ns_][kk_] = *(const bf16x8*)((const char*)sB[d][rl_ >> 7] + swz16(lo_)); \
      }                                                                         \
    }                                                                           \
    __VA_ARGS__;                                                                \
    __builtin_amdgcn_s_barrier();                                               \
    asm volatile("s_waitcnt lgkmcnt(0)" ::: "memory");                          \
    __builtin_amdgcn_sched_barrier(0);                                          \
    __builtin_amdgcn_s_setprio(1);                                              \
    _Pragma("unroll") for (int s_ = 0; s_ < 2; s_++)                            \
    _Pragma("unroll") for (int ns_ = 0; ns_ < 4; ns_++)                         \
    _Pragma("unroll") for (int kk_ = 0; kk_ < 2; kk_++)                         \
      acc[q][s_][ns_] = __builtin_amdgcn_mfma_f32_16x16x32_bf16(                \
          af_[s_][kk_], bfr[ns_][kk_], acc[q][s_][ns_], 0, 0, 0);               \
    __builtin_amdgcn_s_setprio(0);                                              \
    { int wv_ = (WVN);                                                          \
      if (wv_ == 6) { asm volatile("s_waitcnt vmcnt(6)" ::: "memory"); }        \
      else if (wv_ == 0) { asm volatile("s_waitcnt vmcnt(0)" ::: "memory"); } } \
    __builtin_amdgcn_s_barrier();                                               \
  }

template <int OM, int CW, int CH>
__global__ __launch_bounds__(512) void k_gemm8(const u16* __restrict__ A,
                                               const u16* __restrict__ Bm,
                                               void* __restrict__ Cout,
                                               const float* __restrict__ ctab,
                                               const float* __restrict__ stab,
                                               int N, int Kl, int Kstr) {
  __shared__ u16 sA[2][2][8192];   // [dbuf][half][128*64]
  __shared__ u16 sB[2][2][8192];
  constexpr int NBPC = CW * CH;
  const int gx = gridDim.x;
  const int lin = blockIdx.y * gx + blockIdx.x;
  const int c = lin & 7;
  const int idx = lin >> 3;
  const int chunkid = c + 8 * (idx / NBPC);
  const int jj = idx % NBPC;
  const int ncc = gx / CW;
  const int bx = (chunkid % ncc) * CW + jj % CW;
  const int by = (chunkid / ncc) * CH + jj / CW;
  const long m0 = (long)by * 256, n0 = (long)bx * 256;
  const int tid = threadIdx.x;
  const int wid = tid >> 6, lane = tid & 63;
  const int wm = wid >> 2, wn = wid & 3;
  const int lq = lane >> 4, ll = lane & 15;
  const long zoff = (long)blockIdx.z * Kl;

  long aoff[2], boff[2];
#pragma unroll
  for (int j2 = 0; j2 < 2; j2++) {
    int off = j2 * 8192 + wid * 1024 + lane * 16;
    int lo = swz16(off);
    int r = lo >> 7, cc = (lo & 127) >> 1;
    aoff[j2] = (m0 + r) * Kstr + cc + zoff;
    boff[j2] = (n0 + r) * Kstr + cc + zoff;
  }
  const int dst0 = wid * 512;
  const int dst1 = 4096 + wid * 512;

  f32x4 acc[4][2][4] = {};
  bf16x8 bfr[4][2];

  const int NT = Kl >> 6;
  const int NI = NT >> 1;

  STG_A(0, 0, 0); STG_A(0, 1, 0); STG_B(0, 0, 0); STG_B(0, 1, 0);
  STG_B(1, 0, 1); STG_B(1, 1, 1); STG_A(1, 0, 1);
  asm volatile("s_waitcnt vmcnt(6)" ::: "memory");
  __builtin_amdgcn_s_barrier();

  for (int it = 0; it < NI; it++) {
    const int t = 2 * it;
    const bool full = (t + 2 < NT);
    PHASE(0, 0, true,  -1,            STG_A(1, 1, t + 1))
    PHASE(1, 0, false, -1,            if (full) STG_B(0, 0, t + 2))
    PHASE(2, 0, false, -1,            if (full) STG_B(0, 1, t + 2))
    PHASE(3, 0, false, full ? 6 : 0,  if (full) STG_A(0, 0, t + 2))
    PHASE(0, 1, true,  -1,            if (full) STG_A(0, 1, t + 2))
    PHASE(1, 1, false, -1,            if (full) STG_B(1, 0, t + 3))
    PHASE(2, 1, false, -1,            if (full) STG_B(1, 1, t + 3))
    PHASE(3, 1, false, full ? 6 : -1, if (full) STG_A(1, 0, t + 3))
  }

#pragma unroll
  for (int q = 0; q < 4; q++)
#pragma unroll
    for (int s = 0; s < 2; s++) {
      const long row0 = m0 + (q * 4 + wm * 2 + s) * 16 + lq * 4;
      if (OM == 7) {
#pragma unroll
        for (int n2 = 0; n2 < 2; n2++) {
          const long ocol = ((n0 + wn * 64) >> 1) + n2 * 16 + ll;
#pragma unroll
          for (int r = 0; r < 4; r++) {
            float v1 = acc[q][s][n2 * 2][r];
            float v3 = acc[q][s][n2 * 2 + 1][r];
            float g = v1 / (1.0f + __expf(-v1)) * v3;
            ((u16*)Cout)[(row0 + r) * 4096 + ocol] = f2bf(g);
          }
        }
      } else {
#pragma unroll
        for (int ns = 0; ns < 4; ns++) {
          const long col = n0 + wn * 64 + ns * 16 + ll;
#pragma unroll
          for (int r = 0; r < 4; r++) {
            float v = acc[q][s][ns][r];
            long rr = row0 + r;
            if (OM == 3) {
              float v2 = v;
              if (col < 2048) {     // rope on q,k (uniform branch, 256-aligned)
                int d = (int)col & 63;
                int srow = (int)rr & (Ss - 1);
                int p = d >> 1;
                float cs = ctab[srow * 32 + p], sn = stab[srow * 32 + p];
                float o = __shfl_xor(v, 1);
                v2 = (d & 1) ? (o * sn + v * cs) : (v * cs - o * sn);
                if (col < 1024) v2 *= 0.125f;   // fold 1/sqrt(dk) into q
              }
              if (col < 2048) {
                ((u16*)Cout)[(col >> 10) * (long)(Mm * 1024) + rr * 1024 + (col & 1023)] = f2bf(v2);
              } else {
                int d = col & 63, hh = ((int)col >> 6) & 15;
                int b2 = (int)rr >> 11, s2 = (int)rr & (Ss - 1);
                ((u16*)Cout)[(long)(2 * Mm * 1024) + ((long)((b2 * Hh + hh) * DKk + d)) * Ss + s2] = f2bf(v2);
              }
            } else { // OM == 6: bf16 partial at z-slice offset
              ((u16*)Cout)[(long)blockIdx.z * Mm * (long)N + rr * N + col] = f2bf(v);
            }
          }
        }
      }
    }
}

// ---------------- flash attention, paired q-tiles, KVBLK=128 ----------------
constexpr int PPAD = 80;

// Kh: 64-row K half-tile [64][8 chunks swizzled]; Vc: full V tile [64 d-rows][16 chunks]
DEV void attn_tile(const u16* __restrict__ Kh, const u16* __restrict__ Vc, int vcb,
                   u16* __restrict__ myP, const bf16x8* qf, f32x4* accO,
                   float* mrow, float* lrow, int qloc, bool diag, int lq, int ll) {
  f32x4 sacc[4] = {};
  __builtin_amdgcn_s_setprio(1);
#pragma unroll
  for (int fn = 0; fn < 4; fn++)
#pragma unroll
    for (int ks = 0; ks < 2; ks++) {
      bf16x8 kf = *(const bf16x8*)&Kh[(fn * 16 + ll) * 64 + (((ks * 4 + lq) ^ (ll & 7)) * 8)];
      sacc[fn] = __builtin_amdgcn_mfma_f32_16x16x32_bf16(qf[ks], kf, sacc[fn], 0, 0, 0);
    }
  __builtin_amdgcn_s_setprio(0);
  float sv[4][4], pmax[4];
#pragma unroll
  for (int r = 0; r < 4; r++) pmax[r] = -1e30f;
#pragma unroll
  for (int fn = 0; fn < 4; fn++) {
    int kc = fn * 16 + ll;
#pragma unroll
    for (int r = 0; r < 4; r++) {
      float v = sacc[fn][r];
      if (diag && kc > qloc + r) v = -1e30f;
      sv[fn][r] = v;
      pmax[r] = fmaxf(pmax[r], v);
    }
  }
#pragma unroll
  for (int r = 0; r < 4; r++) {
#pragma unroll
    for (int m = 1; m < 16; m <<= 1) pmax[r] = fmaxf(pmax[r], __shfl_xor(pmax[r], m, 64));
  }
  float alpha[4], rsum[4];
#pragma unroll
  for (int r = 0; r < 4; r++) {
    float mnew = fmaxf(mrow[r], pmax[r]);
    alpha[r] = __expf(mrow[r] - mnew);
    mrow[r] = mnew;
    rsum[r] = 0.f;
  }
#pragma unroll
  for (int fn = 0; fn < 4; fn++) {
#pragma unroll
    for (int r = 0; r < 4; r++) {
      float p = __expf(sv[fn][r] - mrow[r]);
      rsum[r] += p;
      myP[(lq * 4 + r) * PPAD + fn * 16 + ll] = f2bf(p);
    }
  }
#pragma unroll
  for (int r = 0; r < 4; r++) {
#pragma unroll
    for (int m = 1; m < 16; m <<= 1) rsum[r] += __shfl_xor(rsum[r], m, 64);
    lrow[r] = lrow[r] * alpha[r] + rsum[r];
  }
#pragma unroll
  for (int fn = 0; fn < 4; fn++)
#pragma unroll
    for (int r = 0; r < 4; r++) accO[fn][r] *= alpha[r];
  bf16x8 pa[2];
#pragma unroll
  for (int ks = 0; ks < 2; ks++)
    pa[ks] = *(const bf16x8*)&myP[ll * PPAD + ks * 32 + lq * 8];
  __builtin_amdgcn_s_setprio(1);
#pragma unroll
  for (int fn = 0; fn < 4; fn++)
#pragma unroll
    for (int ks = 0; ks < 2; ks++) {
      bf16x8 vf = *(const bf16x8*)&Vc[(fn * 16 + ll) * 128 + (((vcb + ks * 4 + lq) ^ (ll & 7)) * 8)];
      accO[fn] = __builtin_amdgcn_mfma_f32_16x16x32_bf16(pa[ks], vf, accO[fn], 0, 0, 0);
    }
  __builtin_amdgcn_s_setprio(0);
}

__global__ __launch_bounds__(256) void k_attn(const u16* __restrict__ Q,
                                              const u16* __restrict__ Kb,
                                              const u16* __restrict__ VT,
                                              u16* __restrict__ O) {
  __shared__ u16 Kt[2][128 * 64];
  __shared__ u16 Vt[2][64 * 128];
  __shared__ u16 P[4][16 * PPAD];
  const int pair = blockIdx.x;   // 0..15
  const int bh = blockIdx.y;     // 0..31
  const int b = bh >> 4, h = bh & 15;
  const int tid = threadIdx.x;
  const int wid = tid >> 6, lane = tid & 63;
  const int lq = lane >> 4, ll = lane & 15;
  const int qtA = pair, qtB = 31 - pair;
  const int qr0A = qtA * 64 + wid * 16;
  const int qr0B = qtB * 64 + wid * 16;
  const int qloc = wid * 16 + lq * 4;
  const long qkbase = ((long)b * Ss) * Dd + h * DKk;
  const long vbase  = ((long)(b * Hh + h) * DKk) * Ss;
  const int nk64 = 32 - pair;
  const int nk128 = (nk64 + 1) >> 1;

  // staging geometry (swizzled), 1024 slots of 16B per tile, 4 per thread
  int kr[4], kc[4], vr[4], vc[4], ldsb[4];
#pragma unroll
  for (int i = 0; i < 4; i++) {
    int s = 256 * i + wid * 64 + lane;
    kr[i] = s >> 3;  kc[i] = (s & 7) ^ (kr[i] & 7);
    vr[i] = s >> 4;  vc[i] = (s & 15) ^ (vr[i] & 7);
    ldsb[i] = (256 * i + wid * 64) * 8;
  }

  bf16x8 qfA[2], qfB[2];
#pragma unroll
  for (int ks = 0; ks < 2; ks++) {
    qfA[ks] = *(const bf16x8*)&Q[qkbase + (long)(qr0A + ll) * Dd + ks * 32 + lq * 8];
    qfB[ks] = *(const bf16x8*)&Q[qkbase + (long)(qr0B + ll) * Dd + ks * 32 + lq * 8];
  }

  f32x4 accA[4] = {}, accB[4] = {};
  float mA[4], lA[4], mB[4], lB[4];
#pragma unroll
  for (int r = 0; r < 4; r++) { mA[r] = mB[r] = -1e30f; lA[r] = lB[r] = 0.f; }
  u16* myP = P[wid];

  // prologue: stage KV block 0
#pragma unroll
  for (int i = 0; i < 4; i++) {
    gload_lds16(Kb + qkbase + (long)kr[i] * Dd + kc[i] * 8, Kt[0] + ldsb[i]);
    gload_lds16(VT + vbase + (long)vr[i] * Ss + vc[i] * 8, Vt[0] + ldsb[i]);
  }
  __syncthreads();

  for (int j = 0; j < nk128; j++) {
    if (j + 1 < nk128) {
      const int kn = (j + 1) * 128;
      u16* kd = Kt[(j + 1) & 1];
      u16* vd = Vt[(j + 1) & 1];
#pragma unroll
      for (int i = 0; i < 4; i++) {
        gload_lds16(Kb + qkbase + (long)(kn + kr[i]) * Dd + kc[i] * 8, kd + ldsb[i]);
        gload_lds16(VT + vbase + (long)vr[i] * Ss + kn + vc[i] * 8, vd + ldsb[i]);
      }
    }
    const u16* Kc = Kt[j & 1];
    const u16* Vc = Vt[j & 1];
#pragma unroll
    for (int hh = 0; hh < 2; hh++) {
      const int kt64 = 2 * j + hh;
      if (kt64 < nk64)
        attn_tile(Kc + hh * 64 * 64, Vc, hh * 8, myP, qfB, accB, mB, lB, qloc,
                  kt64 == nk64 - 1, lq, ll);
      if (kt64 <= pair)
        attn_tile(Kc + hh * 64 * 64, Vc, hh * 8, myP, qfA, accA, mA, lA, qloc,
                  kt64 == pair, lq, ll);
    }
    __syncthreads();
  }

#pragma unroll
  for (int fn = 0; fn < 4; fn++) {
#pragma unroll
    for (int r = 0; r < 4; r++) {
      int rowA = qr0A + lq * 4 + r;
      int rowB = qr0B + lq * 4 + r;
      O[((long)(b * Ss + rowA)) * Dd + h * DKk + fn * 16 + ll] = f2bf(accA[fn][r] / lA[r]);
      O[((long)(b * Ss + rowB)) * Dd + h * DKk + fn * 16 + ll] = f2bf(accB[fn][r] / lB[r]);
    }
  }
}

extern "C" void kernel_launch(void* const* d_in, const int* in_sizes, int n_in,
                              void* d_out, int out_size, void* d_ws, size_t ws_size,
                              hipStream_t stream) {
  const float* x   = (const float*)d_in[0];
  const int*   tp  = (const int*)d_in[1];
  const float* wq  = (const float*)d_in[2];
  const float* wk  = (const float*)d_in[3];
  const float* wv  = (const float*)d_in[4];
  const float* wo  = (const float*)d_in[5];
  const float* ln1 = (const float*)d_in[6];
  const float* ln2 = (const float*)d_in[7];
  const float* w1  = (const float*)d_in[8];
  const float* w2  = (const float*)d_in[9];
  const float* w3  = (const float*)d_in[10];

  char* ws = (char*)d_ws;
  const size_t MB = 1024 * 1024;
  u16*   wqkv_b = (u16*)(ws + 0 * MB);
  u16*   wo_b   = (u16*)(ws + 6 * MB);
  u16*   w13_b  = (u16*)(ws + 8 * MB);    // interleaved w1/w3, 16MB
  u16*   w2_b   = (u16*)(ws + 24 * MB);
  u16*   xn     = (u16*)(ws + 32 * MB);
  float* x2     = (float*)(ws + 40 * MB); // written by WO gemm (after tables dead)
  float* ctab   = (float*)(ws + 40 * MB); // rope tables overlay x2 (dead after QKV)
  float* stab   = ctab + 65536;
  u16*   qb     = (u16*)(ws + 56 * MB);
  u16*   kb     = (u16*)(ws + 64 * MB);
  u16*   vtb    = (u16*)(ws + 72 * MB);
  u16*   ob     = (u16*)(ws + 80 * MB);
  u16*   x1     = (u16*)(ws + 56 * MB);   // gated [4096][4096] (overlays q/k/vt)
  u16*   pparts = (u16*)(ws + 88 * MB);   // 4 x 8MB bf16 partials

  // weights->bf16 (w1/w3 interleaved) + ln1 + rope tables
  k_prep<<<16384 + Mm + 256, 256, 0, stream>>>(wq, wk, wv, wo, w1, w2, w3,
                                               wqkv_b, wo_b, w13_b, w2_b,
                                               x, ln1, xn, tp, ctab, stab);
  // QKV with fused rope (q scaled 1/8) — chunks 3x4 tiles
  k_gemm8<3, 3, 4><<<dim3(12, 16), 512, 0, stream>>>(xn, wqkv_b, qb, ctab, stab, 3072, 1024, 1024);
  k_attn<<<dim3(16, 32), 256, 0, stream>>>(qb, kb, vtb, ob);
  k_gemm<1, true><<<dim3(8, 32), 256, 0, stream>>>(ob, wo_b, x2, x, 1024, 1024, 1024);
  k_rmsnorm<<<Mm, 256, 0, stream>>>(x2, ln2, xn);
  // W13 + in-epilogue SwiGLU -> gated x1 [4096][4096]
  k_gemm8<7, 4, 4><<<dim3(32, 16), 512, 0, stream>>>(xn, w13_b, x1, nullptr, nullptr, 8192, 1024, 1024);
  // W2: 8-phase split-K x4, bf16 partials -> combine
  k_gemm8<6, 4, 2><<<dim3(4, 16, 4), 512, 0, stream>>>(x1, w2_b, pparts, nullptr, nullptr, 1024, 1024, 4096);
  k_addout4<<<4096, 256, 0, stream>>>(pparts, x2, (float*)d_out);
}

// Round 13
// 322.332 us; speedup vs baseline: 1.1334x; 1.1334x over previous
//
#include <hip/hip_runtime.h>
#include <hip/hip_bf16.h>

typedef __attribute__((ext_vector_type(4))) float f32x4;
typedef __attribute__((ext_vector_type(8))) short bf16x8;
typedef unsigned short u16;
typedef unsigned int u32;
typedef __attribute__((ext_vector_type(4))) u16 u16x4;

#define DEV static __device__ __forceinline__

constexpr int Bb = 2, Ss = 2048, Dd = 1024, Hh = 16, DKk = 64;
constexpr int Mm = Bb * Ss;   // 4096 token rows

DEV float bf2f(u16 u) { union { u32 i; float f; } v; v.i = (u32)u << 16; return v.f; }
DEV u16 f2bf(float f) {
  union { float f; u32 i; } v; v.f = f;
  u32 r = v.i + 0x7FFFu + ((v.i >> 16) & 1u);
  return (u16)(r >> 16);
}

DEV void gload_lds16(const u16* g, u16* l) {
  __builtin_amdgcn_global_load_lds((const __attribute__((address_space(1))) u32*)g,
                                   (__attribute__((address_space(3))) u32*)l, 16, 0, 0);
}

// byte-offset swizzle within a 16KB half-tile [128 rows][128B] (involution)
DEV int swz16(int o) {
  return o ^ (((o >> 8) & 1) << 6) ^ (((o >> 9) & 1) << 5);
}

// ---------------- merged: weight convert (blocks 0..16383) + rmsnorm1 (rest) ----------------
// w13 layout: interleaved 16-row groups — B row n: (n>>4) even -> w1, odd -> w3.
__global__ __launch_bounds__(256) void k_prep(const float* __restrict__ wq, const float* __restrict__ wk,
                          const float* __restrict__ wv, const float* __restrict__ wo,
                          const float* __restrict__ w1, const float* __restrict__ w2,
                          const float* __restrict__ w3,
                          u16* __restrict__ wqkv, u16* __restrict__ wob,
                          u16* __restrict__ w13, u16* __restrict__ w2b,
                          const float* __restrict__ x, const float* __restrict__ ln1,
                          u16* __restrict__ xn) {
  if (blockIdx.x < 16384) {
    int i = (blockIdx.x * 256 + threadIdx.x) * 4;
    int seg = i >> 20;
    const float* src; u16* dst;
    if (seg == 0)      { src = wq + i;             dst = wqkv + i; }
    else if (seg == 1) { src = wk + (i - (1<<20)); dst = wqkv + i; }
    else if (seg == 2) { src = wv + (i - (2<<20)); dst = wqkv + i; }
    else if (seg == 3) { src = wo + (i - (3<<20)); dst = wob  + (i - (3<<20)); }
    else if (seg < 8)  {
      int ii = i - (4<<20);
      int ri = ii >> 10, ci = ii & 1023;
      int dr = ((ri >> 4) << 5) + (ri & 15);
      src = w1 + ii; dst = w13 + (long)dr * 1024 + ci;
    }
    else if (seg < 12) { src = w2 + (i - (8<<20)); dst = w2b  + (i - (8<<20)); }
    else {
      int ii = i - (12<<20);
      int ri = ii >> 10, ci = ii & 1023;
      int dr = ((ri >> 4) << 5) + 16 + (ri & 15);
      src = w3 + ii; dst = w13 + (long)dr * 1024 + ci;
    }
    float4 v = *(const float4*)src;
    u16x4 o = { f2bf(v.x), f2bf(v.y), f2bf(v.z), f2bf(v.w) };
    *(u16x4*)dst = o;
  } else {
    int row = blockIdx.x - 16384;
    int t = threadIdx.x;
    float4 v = ((const float4*)(x + (long)row * Dd))[t];
    float ss = v.x * v.x + v.y * v.y + v.z * v.z + v.w * v.w;
#pragma unroll
    for (int m = 32; m; m >>= 1) ss += __shfl_xor(ss, m, 64);
    __shared__ float red[4];
    if ((t & 63) == 0) red[t >> 6] = ss;
    __syncthreads();
    float tot = red[0] + red[1] + red[2] + red[3];
    float r = rsqrtf(tot * (1.0f / Dd) + 1e-5f);
    float4 wv2 = ((const float4*)ln1)[t];
    u16x4 o = { f2bf(v.x * r * wv2.x), f2bf(v.y * r * wv2.y),
                f2bf(v.z * r * wv2.z), f2bf(v.w * r * wv2.w) };
    ((u16x4*)(xn + (long)row * Dd))[t] = o;
  }
}

// ---------------- RMSNorm ----------------
__global__ __launch_bounds__(256) void k_rmsnorm(const float* __restrict__ x,
                                                 const float* __restrict__ w,
                                                 u16* __restrict__ out) {
  int row = blockIdx.x;
  int t = threadIdx.x;
  float4 v = ((const float4*)(x + (long)row * Dd))[t];
  float ss = v.x * v.x + v.y * v.y + v.z * v.z + v.w * v.w;
#pragma unroll
  for (int m = 32; m; m >>= 1) ss += __shfl_xor(ss, m, 64);
  __shared__ float red[4];
  if ((t & 63) == 0) red[t >> 6] = ss;
  __syncthreads();
  float tot = red[0] + red[1] + red[2] + red[3];
  float r = rsqrtf(tot * (1.0f / Dd) + 1e-5f);
  float4 wv = ((const float4*)w)[t];
  u16x4 o = { f2bf(v.x * r * wv.x), f2bf(v.y * r * wv.y),
              f2bf(v.z * r * wv.z), f2bf(v.w * r * wv.w) };
  ((u16x4*)(out + (long)row * Dd))[t] = o;
}

// ---------------- RoPE (q scaled by 1/8) ----------------
__global__ void k_rope(u16* __restrict__ q, u16* __restrict__ k, const int* __restrict__ tp) {
  int idx = blockIdx.x * 256 + threadIdx.x;
  if (idx >= Bb * Ss * Hh * 32) return;
  int p = idx & 31;
  int h = (idx >> 5) & 15;
  int row = idx >> 9;
  int s = row & (Ss - 1);
  float pos = (float)tp[s];
  float invf = __expf(-(float)p * (2.0f / DKk) * 9.2103403719761836f);
  float fr = pos * invf;
  float sn, cs;
  sincosf(fr, &sn, &cs);
  long base = (long)row * Dd + h * DKk + 2 * p;
  float xe = bf2f(q[base]), xo = bf2f(q[base + 1]);
  q[base]     = f2bf((xe * cs - xo * sn) * 0.125f);
  q[base + 1] = f2bf((xe * sn + xo * cs) * 0.125f);
  xe = bf2f(k[base]); xo = bf2f(k[base + 1]);
  k[base]     = f2bf(xe * cs - xo * sn);
  k[base + 1] = f2bf(xe * sn + xo * cs);
}

// ---------------- final reduce: out = sum(4 bf16 partials) + x2 ----------------
__global__ void k_addout4(const u16* __restrict__ p, const float* __restrict__ x2,
                          float* __restrict__ out) {
  int i = (blockIdx.x * 256 + threadIdx.x) * 4;
  float4 c = *(const float4*)(x2 + i);
  float s0 = c.x, s1 = c.y, s2 = c.z, s3 = c.w;
#pragma unroll
  for (int z = 0; z < 4; z++) {
    u16x4 a = *(const u16x4*)(p + (long)z * Mm * 1024 + i);
    s0 += bf2f(a[0]); s1 += bf2f(a[1]); s2 += bf2f(a[2]); s3 += bf2f(a[3]);
  }
  float4 o = { s0, s1, s2, s3 };
  *(float4*)(out + i) = o;
}

// ---------------- m97-style 128x128 NT GEMM (WO) ----------------
template <int OM, bool RES>
__global__ __launch_bounds__(256) void k_gemm(const u16* __restrict__ A,
                                              const u16* __restrict__ Bm,
                                              void* __restrict__ Cout,
                                              const float* __restrict__ Rres,
                                              int N, int Kl, int Kstr) {
  __shared__ u16 Abuf[128 * 32];
  __shared__ u16 Bbuf[128 * 32];
  const int tid = threadIdx.x;
  const int wid = tid >> 6, lane = tid & 63;
  const int wm = wid >> 1, wn = wid & 1;
  const int lq = lane >> 4, ll = lane & 15;
  const int lin = blockIdx.y * gridDim.x + blockIdx.x;
  const int c = lin & 7, j = lin >> 3;
  const int ncc = gridDim.x >> 2;
  const int bxc = (c % ncc) * 4 + (j & 3);
  const int byc = (c / ncc) * 8 + (j >> 2);
  const int m0 = byc * 128, n0 = bxc * 128;

  const u16* Ap = A + (long)blockIdx.z * Kl;
  const u16* Bp = Bm + (long)blockIdx.z * Kl;

  f32x4 acc[4][4] = {};

  const int srow = tid >> 2;
  const int scol = (tid & 3) * 8;
  const long aoff = (long)(m0 + srow) * Kstr + scol;
  const long boff = (long)(n0 + srow) * Kstr + scol;
  u16* aldsw = Abuf + wid * 512;
  u16* bldsw = Bbuf + wid * 512;

  for (int k0 = 0; k0 < Kl; k0 += 32) {
    __syncthreads();
    gload_lds16(Ap + aoff + k0, aldsw);
    gload_lds16(Ap + aoff + (long)64 * Kstr + k0, aldsw + 2048);
    gload_lds16(Bp + boff + k0, bldsw);
    gload_lds16(Bp + boff + (long)64 * Kstr + k0, bldsw + 2048);
    __syncthreads();
    bf16x8 af[4], bfr[4];
#pragma unroll
    for (int i = 0; i < 4; i++)
      af[i] = *(const bf16x8*)&Abuf[(wm * 64 + i * 16 + ll) * 32 + lq * 8];
#pragma unroll
    for (int j2 = 0; j2 < 4; j2++)
      bfr[j2] = *(const bf16x8*)&Bbuf[(wn * 64 + j2 * 16 + ll) * 32 + lq * 8];
#pragma unroll
    for (int i = 0; i < 4; i++)
#pragma unroll
      for (int j2 = 0; j2 < 4; j2++)
        acc[i][j2] = __builtin_amdgcn_mfma_f32_16x16x32_bf16(af[i], bfr[j2], acc[i][j2], 0, 0, 0);
  }

  float* fout = (float*)Cout + (long)blockIdx.z * Mm * (long)N;
#pragma unroll
  for (int i = 0; i < 4; i++) {
    const int rowb = m0 + wm * 64 + i * 16 + lq * 4;
#pragma unroll
    for (int j2 = 0; j2 < 4; j2++) {
      const int col = n0 + wn * 64 + j2 * 16 + ll;
#pragma unroll
      for (int r = 0; r < 4; r++) {
        int rr = rowb + r;
        float v = acc[i][j2][r];
        if (RES) v += Rres[(long)rr * N + col];
        if (OM == 1) {
          fout[(long)rr * N + col] = v;
        } else {
          ((u16*)Cout)[(long)rr * N + col] = f2bf(v);
        }
      }
    }
  }
}

// ---------------- 256x256 8-phase GEMM (m201 template) ----------------
// OM: 3 = fused qkv epilogue; 6 = split-K bf16 partial; 7 = interleaved W13+SwiGLU
#define STG_A(d, h, kt)                                                         \
  { gload_lds16(A + aoff[0] + (long)(h) * 128 * Kstr + (kt) * 64, &sA[d][h][dst0]); \
    gload_lds16(A + aoff[1] + (long)(h) * 128 * Kstr + (kt) * 64, &sA[d][h][dst1]); }
#define STG_B(d, h, kt)                                                         \
  { gload_lds16(Bm + boff[0] + (long)(h) * 128 * Kstr + (kt) * 64, &sB[d][h][dst0]); \
    gload_lds16(Bm + boff[1] + (long)(h) * 128 * Kstr + (kt) * 64, &sB[d][h][dst1]); }

#define PHASE(q, d, DOB, WVN, ...)                                              \
  {                                                                             \
    bf16x8 af_[2][2];                                                           \
    _Pragma("unroll") for (int s_ = 0; s_ < 2; s_++)                            \
    _Pragma("unroll") for (int kk_ = 0; kk_ < 2; kk_++) {                       \
      int ms_ = (q) * 4 + wm * 2 + s_;                                          \
      int lo_ = ((ms_ & 7) * 16 + ll) * 128 + kk_ * 64 + lq * 16;               \
      af_[s_][kk_] = *(const bf16x8*)((const char*)sA[d][ms_ >> 3] + swz16(lo_)); \
    }                                                                           \
    if (DOB) {                                                                  \
      _Pragma("unroll") for (int ns_ = 0; ns_ < 4; ns_++)                       \
      _Pragma("unroll") for (int kk_ = 0; kk_ < 2; kk_++) {                     \
        int rl_ = wn * 64 + ns_ * 16 + ll;                                      \
        int lo_ = (rl_ & 127) * 128 + kk_ * 64 + lq * 16;                       \
        bfr[ns_][kk_] = *(const bf16x8*)((const char*)sB[d][rl_ >> 7] + swz16(lo_)); \
      }                                                                         \
    }                                                                           \
    __VA_ARGS__;                                                                \
    __builtin_amdgcn_s_barrier();                                               \
    asm volatile("s_waitcnt lgkmcnt(0)" ::: "memory");                          \
    __builtin_amdgcn_sched_barrier(0);                                          \
    __builtin_amdgcn_s_setprio(1);                                              \
    _Pragma("unroll") for (int s_ = 0; s_ < 2; s_++)                            \
    _Pragma("unroll") for (int ns_ = 0; ns_ < 4; ns_++)                         \
    _Pragma("unroll") for (int kk_ = 0; kk_ < 2; kk_++)                         \
      acc[q][s_][ns_] = __builtin_amdgcn_mfma_f32_16x16x32_bf16(                \
          af_[s_][kk_], bfr[ns_][kk_], acc[q][s_][ns_], 0, 0, 0);               \
    __builtin_amdgcn_s_setprio(0);                                              \
    { int wv_ = (WVN);                                                          \
      if (wv_ == 6) { asm volatile("s_waitcnt vmcnt(6)" ::: "memory"); }        \
      else if (wv_ == 0) { asm volatile("s_waitcnt vmcnt(0)" ::: "memory"); } } \
    __builtin_amdgcn_s_barrier();                                               \
  }

// L2-fit chunk map, sequential chunk-rounds per XCD.
template <int OM, int CW, int CH>
__global__ __launch_bounds__(512) void k_gemm8(const u16* __restrict__ A,
                                               const u16* __restrict__ Bm,
                                               void* __restrict__ Cout,
                                               int N, int Kl, int Kstr) {
  __shared__ u16 sA[2][2][8192];   // [dbuf][half][128*64]
  __shared__ u16 sB[2][2][8192];
  constexpr int NBPC = CW * CH;
  const int gx = gridDim.x;
  const int lin = blockIdx.y * gx + blockIdx.x;
  const int c = lin & 7;
  const int idx = lin >> 3;
  const int chunkid = c + 8 * (idx / NBPC);
  const int jj = idx % NBPC;
  const int ncc = gx / CW;
  const int bx = (chunkid % ncc) * CW + jj % CW;
  const int by = (chunkid / ncc) * CH + jj / CW;
  const long m0 = (long)by * 256, n0 = (long)bx * 256;
  const int tid = threadIdx.x;
  const int wid = tid >> 6, lane = tid & 63;
  const int wm = wid >> 2, wn = wid & 3;
  const int lq = lane >> 4, ll = lane & 15;
  const long zoff = (long)blockIdx.z * Kl;

  long aoff[2], boff[2];
#pragma unroll
  for (int j2 = 0; j2 < 2; j2++) {
    int off = j2 * 8192 + wid * 1024 + lane * 16;
    int lo = swz16(off);
    int r = lo >> 7, cc = (lo & 127) >> 1;
    aoff[j2] = (m0 + r) * Kstr + cc + zoff;
    boff[j2] = (n0 + r) * Kstr + cc + zoff;
  }
  const int dst0 = wid * 512;
  const int dst1 = 4096 + wid * 512;

  f32x4 acc[4][2][4] = {};
  bf16x8 bfr[4][2];

  const int NT = Kl >> 6;
  const int NI = NT >> 1;

  STG_A(0, 0, 0); STG_A(0, 1, 0); STG_B(0, 0, 0); STG_B(0, 1, 0);
  STG_B(1, 0, 1); STG_B(1, 1, 1); STG_A(1, 0, 1);
  asm volatile("s_waitcnt vmcnt(6)" ::: "memory");
  __builtin_amdgcn_s_barrier();

  for (int it = 0; it < NI; it++) {
    const int t = 2 * it;
    const bool full = (t + 2 < NT);
    PHASE(0, 0, true,  -1,            STG_A(1, 1, t + 1))
    PHASE(1, 0, false, -1,            if (full) STG_B(0, 0, t + 2))
    PHASE(2, 0, false, -1,            if (full) STG_B(0, 1, t + 2))
    PHASE(3, 0, false, full ? 6 : 0,  if (full) STG_A(0, 0, t + 2))
    PHASE(0, 1, true,  -1,            if (full) STG_A(0, 1, t + 2))
    PHASE(1, 1, false, -1,            if (full) STG_B(1, 0, t + 3))
    PHASE(2, 1, false, -1,            if (full) STG_B(1, 1, t + 3))
    PHASE(3, 1, false, full ? 6 : -1, if (full) STG_A(1, 0, t + 3))
  }

#pragma unroll
  for (int q = 0; q < 4; q++)
#pragma unroll
    for (int s = 0; s < 2; s++) {
      const long row0 = m0 + (q * 4 + wm * 2 + s) * 16 + lq * 4;
      if (OM == 7) {
        // interleaved SwiGLU: ns even = x1, ns odd = x3, same out col
#pragma unroll
        for (int n2 = 0; n2 < 2; n2++) {
          const long ocol = ((n0 + wn * 64) >> 1) + n2 * 16 + ll;
#pragma unroll
          for (int r = 0; r < 4; r++) {
            float v1 = acc[q][s][n2 * 2][r];
            float v3 = acc[q][s][n2 * 2 + 1][r];
            float g = v1 / (1.0f + __expf(-v1)) * v3;
            ((u16*)Cout)[(row0 + r) * 4096 + ocol] = f2bf(g);
          }
        }
      } else {
#pragma unroll
        for (int ns = 0; ns < 4; ns++) {
          const long col = n0 + wn * 64 + ns * 16 + ll;
#pragma unroll
          for (int r = 0; r < 4; r++) {
            float v = acc[q][s][ns][r];
            long rr = row0 + r;
            if (OM == 3) {
              if (col < 2048) {
                ((u16*)Cout)[(col >> 10) * (long)(Mm * 1024) + rr * 1024 + (col & 1023)] = f2bf(v);
              } else {
                int d = col & 63, hh = ((int)col >> 6) & 15;
                int b2 = (int)rr >> 11, s2 = (int)rr & (Ss - 1);
                ((u16*)Cout)[(long)(2 * Mm * 1024) + ((long)((b2 * Hh + hh) * DKk + d)) * Ss + s2] = f2bf(v);
              }
            } else { // OM == 6: bf16 partial at z-slice offset
              ((u16*)Cout)[(long)blockIdx.z * Mm * (long)N + rr * N + col] = f2bf(v);
            }
          }
        }
      }
    }
}

// ---------------- flash attention, paired q-tiles, KVBLK=128 ----------------
constexpr int PPAD = 80;

// Kh: 64-row K half-tile [64][8 chunks swizzled]; Vc: full V tile [64 d-rows][16 chunks]
DEV void attn_tile(const u16* __restrict__ Kh, const u16* __restrict__ Vc, int vcb,
                   u16* __restrict__ myP, const bf16x8* qf, f32x4* accO,
                   float* mrow, float* lrow, int qloc, bool diag, int lq, int ll) {
  f32x4 sacc[4] = {};
  __builtin_amdgcn_s_setprio(1);
#pragma unroll
  for (int fn = 0; fn < 4; fn++)
#pragma unroll
    for (int ks = 0; ks < 2; ks++) {
      bf16x8 kf = *(const bf16x8*)&Kh[(fn * 16 + ll) * 64 + (((ks * 4 + lq) ^ (ll & 7)) * 8)];
      sacc[fn] = __builtin_amdgcn_mfma_f32_16x16x32_bf16(qf[ks], kf, sacc[fn], 0, 0, 0);
    }
  __builtin_amdgcn_s_setprio(0);
  float sv[4][4], pmax[4];
#pragma unroll
  for (int r = 0; r < 4; r++) pmax[r] = -1e30f;
#pragma unroll
  for (int fn = 0; fn < 4; fn++) {
    int kc = fn * 16 + ll;
#pragma unroll
    for (int r = 0; r < 4; r++) {
      float v = sacc[fn][r];
      if (diag && kc > qloc + r) v = -1e30f;
      sv[fn][r] = v;
      pmax[r] = fmaxf(pmax[r], v);
    }
  }
#pragma unroll
  for (int r = 0; r < 4; r++) {
#pragma unroll
    for (int m = 1; m < 16; m <<= 1) pmax[r] = fmaxf(pmax[r], __shfl_xor(pmax[r], m, 64));
  }
  float alpha[4], rsum[4];
#pragma unroll
  for (int r = 0; r < 4; r++) {
    float mnew = fmaxf(mrow[r], pmax[r]);
    alpha[r] = __expf(mrow[r] - mnew);
    mrow[r] = mnew;
    rsum[r] = 0.f;
  }
#pragma unroll
  for (int fn = 0; fn < 4; fn++) {
#pragma unroll
    for (int r = 0; r < 4; r++) {
      float p = __expf(sv[fn][r] - mrow[r]);
      rsum[r] += p;
      myP[(lq * 4 + r) * PPAD + fn * 16 + ll] = f2bf(p);
    }
  }
#pragma unroll
  for (int r = 0; r < 4; r++) {
#pragma unroll
    for (int m = 1; m < 16; m <<= 1) rsum[r] += __shfl_xor(rsum[r], m, 64);
    lrow[r] = lrow[r] * alpha[r] + rsum[r];
  }
#pragma unroll
  for (int fn = 0; fn < 4; fn++)
#pragma unroll
    for (int r = 0; r < 4; r++) accO[fn][r] *= alpha[r];
  bf16x8 pa[2];
#pragma unroll
  for (int ks = 0; ks < 2; ks++)
    pa[ks] = *(const bf16x8*)&myP[ll * PPAD + ks * 32 + lq * 8];
  __builtin_amdgcn_s_setprio(1);
#pragma unroll
  for (int fn = 0; fn < 4; fn++)
#pragma unroll
    for (int ks = 0; ks < 2; ks++) {
      bf16x8 vf = *(const bf16x8*)&Vc[(fn * 16 + ll) * 128 + (((vcb + ks * 4 + lq) ^ (ll & 7)) * 8)];
      accO[fn] = __builtin_amdgcn_mfma_f32_16x16x32_bf16(pa[ks], vf, accO[fn], 0, 0, 0);
    }
  __builtin_amdgcn_s_setprio(0);
}

__global__ __launch_bounds__(256) void k_attn(const u16* __restrict__ Q,
                                              const u16* __restrict__ Kb,
                                              const u16* __restrict__ VT,
                                              u16* __restrict__ O) {
  __shared__ u16 Kt[2][128 * 64];
  __shared__ u16 Vt[2][64 * 128];
  __shared__ u16 P[4][16 * PPAD];
  const int pair = blockIdx.x;   // 0..15
  const int bh = blockIdx.y;     // 0..31
  const int b = bh >> 4, h = bh & 15;
  const int tid = threadIdx.x;
  const int wid = tid >> 6, lane = tid & 63;
  const int lq = lane >> 4, ll = lane & 15;
  const int qtA = pair, qtB = 31 - pair;
  const int qr0A = qtA * 64 + wid * 16;
  const int qr0B = qtB * 64 + wid * 16;
  const int qloc = wid * 16 + lq * 4;
  const long qkbase = ((long)b * Ss) * Dd + h * DKk;
  const long vbase  = ((long)(b * Hh + h) * DKk) * Ss;
  const int nk64 = 32 - pair;
  const int nk128 = (nk64 + 1) >> 1;

  // staging geometry (swizzled), 1024 slots of 16B per tile, 4 per thread
  int kr[4], kc[4], vr[4], vc[4], ldsb[4];
#pragma unroll
  for (int i = 0; i < 4; i++) {
    int s = 256 * i + wid * 64 + lane;
    kr[i] = s >> 3;  kc[i] = (s & 7) ^ (kr[i] & 7);
    vr[i] = s >> 4;  vc[i] = (s & 15) ^ (vr[i] & 7);
    ldsb[i] = (256 * i + wid * 64) * 8;
  }

  bf16x8 qfA[2], qfB[2];
#pragma unroll
  for (int ks = 0; ks < 2; ks++) {
    qfA[ks] = *(const bf16x8*)&Q[qkbase + (long)(qr0A + ll) * Dd + ks * 32 + lq * 8];
    qfB[ks] = *(const bf16x8*)&Q[qkbase + (long)(qr0B + ll) * Dd + ks * 32 + lq * 8];
  }

  f32x4 accA[4] = {}, accB[4] = {};
  float mA[4], lA[4], mB[4], lB[4];
#pragma unroll
  for (int r = 0; r < 4; r++) { mA[r] = mB[r] = -1e30f; lA[r] = lB[r] = 0.f; }
  u16* myP = P[wid];

  // prologue: stage KV block 0
#pragma unroll
  for (int i = 0; i < 4; i++) {
    gload_lds16(Kb + qkbase + (long)kr[i] * Dd + kc[i] * 8, Kt[0] + ldsb[i]);
    gload_lds16(VT + vbase + (long)vr[i] * Ss + vc[i] * 8, Vt[0] + ldsb[i]);
  }
  __syncthreads();

  for (int j = 0; j < nk128; j++) {
    if (j + 1 < nk128) {
      const int kn = (j + 1) * 128;
      u16* kd = Kt[(j + 1) & 1];
      u16* vd = Vt[(j + 1) & 1];
#pragma unroll
      for (int i = 0; i < 4; i++) {
        gload_lds16(Kb + qkbase + (long)(kn + kr[i]) * Dd + kc[i] * 8, kd + ldsb[i]);
        gload_lds16(VT + vbase + (long)vr[i] * Ss + kn + vc[i] * 8, vd + ldsb[i]);
      }
    }
    const u16* Kc = Kt[j & 1];
    const u16* Vc = Vt[j & 1];
#pragma unroll
    for (int hh = 0; hh < 2; hh++) {
      const int kt64 = 2 * j + hh;
      if (kt64 < nk64)
        attn_tile(Kc + hh * 64 * 64, Vc, hh * 8, myP, qfB, accB, mB, lB, qloc,
                  kt64 == nk64 - 1, lq, ll);
      if (kt64 <= pair)
        attn_tile(Kc + hh * 64 * 64, Vc, hh * 8, myP, qfA, accA, mA, lA, qloc,
                  kt64 == pair, lq, ll);
    }
    __syncthreads();
  }

#pragma unroll
  for (int fn = 0; fn < 4; fn++) {
#pragma unroll
    for (int r = 0; r < 4; r++) {
      int rowA = qr0A + lq * 4 + r;
      int rowB = qr0B + lq * 4 + r;
      O[((long)(b * Ss + rowA)) * Dd + h * DKk + fn * 16 + ll] = f2bf(accA[fn][r] / lA[r]);
      O[((long)(b * Ss + rowB)) * Dd + h * DKk + fn * 16 + ll] = f2bf(accB[fn][r] / lB[r]);
    }
  }
}

extern "C" void kernel_launch(void* const* d_in, const int* in_sizes, int n_in,
                              void* d_out, int out_size, void* d_ws, size_t ws_size,
                              hipStream_t stream) {
  const float* x   = (const float*)d_in[0];
  const int*   tp  = (const int*)d_in[1];
  const float* wq  = (const float*)d_in[2];
  const float* wk  = (const float*)d_in[3];
  const float* wv  = (const float*)d_in[4];
  const float* wo  = (const float*)d_in[5];
  const float* ln1 = (const float*)d_in[6];
  const float* ln2 = (const float*)d_in[7];
  const float* w1  = (const float*)d_in[8];
  const float* w2  = (const float*)d_in[9];
  const float* w3  = (const float*)d_in[10];

  char* ws = (char*)d_ws;
  const size_t MB = 1024 * 1024;
  u16*   wqkv_b = (u16*)(ws + 0 * MB);
  u16*   wo_b   = (u16*)(ws + 6 * MB);
  u16*   w13_b  = (u16*)(ws + 8 * MB);    // interleaved w1/w3, 16MB
  u16*   w2_b   = (u16*)(ws + 24 * MB);
  u16*   xn     = (u16*)(ws + 32 * MB);
  float* x2     = (float*)(ws + 40 * MB);
  u16*   qb     = (u16*)(ws + 56 * MB);
  u16*   kb     = (u16*)(ws + 64 * MB);
  u16*   vtb    = (u16*)(ws + 72 * MB);
  u16*   ob     = (u16*)(ws + 80 * MB);
  u16*   x1     = (u16*)(ws + 56 * MB);   // gated [4096][4096] (overlays q/k/vt)
  u16*   pparts = (u16*)(ws + 88 * MB);   // 4 x 8MB bf16 partials

  // weights->bf16 (w1/w3 interleaved) + ln1
  k_prep<<<16384 + Mm, 256, 0, stream>>>(wq, wk, wv, wo, w1, w2, w3,
                                         wqkv_b, wo_b, w13_b, w2_b, x, ln1, xn);
  // QKV: chunks 3x4 tiles
  k_gemm8<3, 3, 4><<<dim3(12, 16), 512, 0, stream>>>(xn, wqkv_b, qb, 3072, 1024, 1024);
  k_rope<<<(Bb * Ss * Hh * 32) / 256, 256, 0, stream>>>(qb, kb, tp);
  k_attn<<<dim3(16, 32), 256, 0, stream>>>(qb, kb, vtb, ob);
  k_gemm<1, true><<<dim3(8, 32), 256, 0, stream>>>(ob, wo_b, x2, x, 1024, 1024, 1024);
  k_rmsnorm<<<Mm, 256, 0, stream>>>(x2, ln2, xn);
  // W13 + in-epilogue SwiGLU -> gated x1 [4096][4096]
  k_gemm8<7, 4, 4><<<dim3(32, 16), 512, 0, stream>>>(xn, w13_b, x1, 8192, 1024, 1024);
  // W2: 8-phase split-K x4, bf16 partials -> combine
  k_gemm8<6, 4, 2><<<dim3(4, 16, 4), 512, 0, stream>>>(x1, w2_b, pparts, 1024, 1024, 4096);
  k_addout4<<<4096, 256, 0, stream>>>(pparts, x2, (float*)d_out);
}

// Round 14
// 314.518 us; speedup vs baseline: 1.1615x; 1.0248x over previous
//
#include <hip/hip_runtime.h>
#include <hip/hip_bf16.h>

typedef __attribute__((ext_vector_type(4))) float f32x4;
typedef __attribute__((ext_vector_type(8))) short bf16x8;
typedef unsigned short u16;
typedef unsigned int u32;
typedef __attribute__((ext_vector_type(4))) u16 u16x4;

#define DEV static __device__ __forceinline__

constexpr int Bb = 2, Ss = 2048, Dd = 1024, Hh = 16, DKk = 64;
constexpr int Mm = Bb * Ss;   // 4096 token rows

DEV float bf2f(u16 u) { union { u32 i; float f; } v; v.i = (u32)u << 16; return v.f; }
DEV u16 f2bf(float f) {
  union { float f; u32 i; } v; v.f = f;
  u32 r = v.i + 0x7FFFu + ((v.i >> 16) & 1u);
  return (u16)(r >> 16);
}

DEV void gload_lds16(const u16* g, u16* l) {
  __builtin_amdgcn_global_load_lds((const __attribute__((address_space(1))) u32*)g,
                                   (__attribute__((address_space(3))) u32*)l, 16, 0, 0);
}

// byte-offset swizzle within a 16KB half-tile [128 rows][128B] (involution)
DEV int swz16(int o) {
  return o ^ (((o >> 8) & 1) << 6) ^ (((o >> 9) & 1) << 5);
}

// ---------------- merged: weight convert (blocks 0..16383) + rmsnorm1 (rest) ----------------
// w13 layout: interleaved 16-row groups — B row n: (n>>4) even -> w1, odd -> w3.
__global__ __launch_bounds__(256) void k_prep(const float* __restrict__ wq, const float* __restrict__ wk,
                          const float* __restrict__ wv, const float* __restrict__ wo,
                          const float* __restrict__ w1, const float* __restrict__ w2,
                          const float* __restrict__ w3,
                          u16* __restrict__ wqkv, u16* __restrict__ wob,
                          u16* __restrict__ w13, u16* __restrict__ w2b,
                          const float* __restrict__ x, const float* __restrict__ ln1,
                          u16* __restrict__ xn) {
  if (blockIdx.x < 16384) {
    int i = (blockIdx.x * 256 + threadIdx.x) * 4;
    int seg = i >> 20;
    const float* src; u16* dst;
    if (seg == 0)      { src = wq + i;             dst = wqkv + i; }
    else if (seg == 1) { src = wk + (i - (1<<20)); dst = wqkv + i; }
    else if (seg == 2) { src = wv + (i - (2<<20)); dst = wqkv + i; }
    else if (seg == 3) { src = wo + (i - (3<<20)); dst = wob  + (i - (3<<20)); }
    else if (seg < 8)  {
      int ii = i - (4<<20);
      int ri = ii >> 10, ci = ii & 1023;
      int dr = ((ri >> 4) << 5) + (ri & 15);
      src = w1 + ii; dst = w13 + (long)dr * 1024 + ci;
    }
    else if (seg < 12) { src = w2 + (i - (8<<20)); dst = w2b  + (i - (8<<20)); }
    else {
      int ii = i - (12<<20);
      int ri = ii >> 10, ci = ii & 1023;
      int dr = ((ri >> 4) << 5) + 16 + (ri & 15);
      src = w3 + ii; dst = w13 + (long)dr * 1024 + ci;
    }
    float4 v = *(const float4*)src;
    u16x4 o = { f2bf(v.x), f2bf(v.y), f2bf(v.z), f2bf(v.w) };
    *(u16x4*)dst = o;
  } else {
    int row = blockIdx.x - 16384;
    int t = threadIdx.x;
    float4 v = ((const float4*)(x + (long)row * Dd))[t];
    float ss = v.x * v.x + v.y * v.y + v.z * v.z + v.w * v.w;
#pragma unroll
    for (int m = 32; m; m >>= 1) ss += __shfl_xor(ss, m, 64);
    __shared__ float red[4];
    if ((t & 63) == 0) red[t >> 6] = ss;
    __syncthreads();
    float tot = red[0] + red[1] + red[2] + red[3];
    float r = rsqrtf(tot * (1.0f / Dd) + 1e-5f);
    float4 wv2 = ((const float4*)ln1)[t];
    u16x4 o = { f2bf(v.x * r * wv2.x), f2bf(v.y * r * wv2.y),
                f2bf(v.z * r * wv2.z), f2bf(v.w * r * wv2.w) };
    ((u16x4*)(xn + (long)row * Dd))[t] = o;
  }
}

// ---------------- RMSNorm ----------------
__global__ __launch_bounds__(256) void k_rmsnorm(const float* __restrict__ x,
                                                 const float* __restrict__ w,
                                                 u16* __restrict__ out) {
  int row = blockIdx.x;
  int t = threadIdx.x;
  float4 v = ((const float4*)(x + (long)row * Dd))[t];
  float ss = v.x * v.x + v.y * v.y + v.z * v.z + v.w * v.w;
#pragma unroll
  for (int m = 32; m; m >>= 1) ss += __shfl_xor(ss, m, 64);
  __shared__ float red[4];
  if ((t & 63) == 0) red[t >> 6] = ss;
  __syncthreads();
  float tot = red[0] + red[1] + red[2] + red[3];
  float r = rsqrtf(tot * (1.0f / Dd) + 1e-5f);
  float4 wv = ((const float4*)w)[t];
  u16x4 o = { f2bf(v.x * r * wv.x), f2bf(v.y * r * wv.y),
              f2bf(v.z * r * wv.z), f2bf(v.w * r * wv.w) };
  ((u16x4*)(out + (long)row * Dd))[t] = o;
}

// ---------------- RoPE (q scaled by 1/8) ----------------
__global__ void k_rope(u16* __restrict__ q, u16* __restrict__ k, const int* __restrict__ tp) {
  int idx = blockIdx.x * 256 + threadIdx.x;
  if (idx >= Bb * Ss * Hh * 32) return;
  int p = idx & 31;
  int h = (idx >> 5) & 15;
  int row = idx >> 9;
  int s = row & (Ss - 1);
  float pos = (float)tp[s];
  float invf = __expf(-(float)p * (2.0f / DKk) * 9.2103403719761836f);
  float fr = pos * invf;
  float sn, cs;
  sincosf(fr, &sn, &cs);
  long base = (long)row * Dd + h * DKk + 2 * p;
  float xe = bf2f(q[base]), xo = bf2f(q[base + 1]);
  q[base]     = f2bf((xe * cs - xo * sn) * 0.125f);
  q[base + 1] = f2bf((xe * sn + xo * cs) * 0.125f);
  xe = bf2f(k[base]); xo = bf2f(k[base + 1]);
  k[base]     = f2bf(xe * cs - xo * sn);
  k[base + 1] = f2bf(xe * sn + xo * cs);
}

// ---------------- final reduce: out = sum(4 bf16 partials) + x2 ----------------
__global__ void k_addout4(const u16* __restrict__ p, const float* __restrict__ x2,
                          float* __restrict__ out) {
  int i = (blockIdx.x * 256 + threadIdx.x) * 4;
  float4 c = *(const float4*)(x2 + i);
  float s0 = c.x, s1 = c.y, s2 = c.z, s3 = c.w;
#pragma unroll
  for (int z = 0; z < 4; z++) {
    u16x4 a = *(const u16x4*)(p + (long)z * Mm * 1024 + i);
    s0 += bf2f(a[0]); s1 += bf2f(a[1]); s2 += bf2f(a[2]); s3 += bf2f(a[3]);
  }
  float4 o = { s0, s1, s2, s3 };
  *(float4*)(out + i) = o;
}

// ---------------- m97-style 128x128 NT GEMM (WO) ----------------
template <int OM, bool RES>
__global__ __launch_bounds__(256) void k_gemm(const u16* __restrict__ A,
                                              const u16* __restrict__ Bm,
                                              void* __restrict__ Cout,
                                              const float* __restrict__ Rres,
                                              int N, int Kl, int Kstr) {
  __shared__ u16 Abuf[128 * 32];
  __shared__ u16 Bbuf[128 * 32];
  const int tid = threadIdx.x;
  const int wid = tid >> 6, lane = tid & 63;
  const int wm = wid >> 1, wn = wid & 1;
  const int lq = lane >> 4, ll = lane & 15;
  const int lin = blockIdx.y * gridDim.x + blockIdx.x;
  const int c = lin & 7, j = lin >> 3;
  const int ncc = gridDim.x >> 2;
  const int bxc = (c % ncc) * 4 + (j & 3);
  const int byc = (c / ncc) * 8 + (j >> 2);
  const int m0 = byc * 128, n0 = bxc * 128;

  const u16* Ap = A + (long)blockIdx.z * Kl;
  const u16* Bp = Bm + (long)blockIdx.z * Kl;

  f32x4 acc[4][4] = {};

  const int srow = tid >> 2;
  const int scol = (tid & 3) * 8;
  const long aoff = (long)(m0 + srow) * Kstr + scol;
  const long boff = (long)(n0 + srow) * Kstr + scol;
  u16* aldsw = Abuf + wid * 512;
  u16* bldsw = Bbuf + wid * 512;

  for (int k0 = 0; k0 < Kl; k0 += 32) {
    __syncthreads();
    gload_lds16(Ap + aoff + k0, aldsw);
    gload_lds16(Ap + aoff + (long)64 * Kstr + k0, aldsw + 2048);
    gload_lds16(Bp + boff + k0, bldsw);
    gload_lds16(Bp + boff + (long)64 * Kstr + k0, bldsw + 2048);
    __syncthreads();
    bf16x8 af[4], bfr[4];
#pragma unroll
    for (int i = 0; i < 4; i++)
      af[i] = *(const bf16x8*)&Abuf[(wm * 64 + i * 16 + ll) * 32 + lq * 8];
#pragma unroll
    for (int j2 = 0; j2 < 4; j2++)
      bfr[j2] = *(const bf16x8*)&Bbuf[(wn * 64 + j2 * 16 + ll) * 32 + lq * 8];
#pragma unroll
    for (int i = 0; i < 4; i++)
#pragma unroll
      for (int j2 = 0; j2 < 4; j2++)
        acc[i][j2] = __builtin_amdgcn_mfma_f32_16x16x32_bf16(af[i], bfr[j2], acc[i][j2], 0, 0, 0);
  }

  float* fout = (float*)Cout + (long)blockIdx.z * Mm * (long)N;
#pragma unroll
  for (int i = 0; i < 4; i++) {
    const int rowb = m0 + wm * 64 + i * 16 + lq * 4;
#pragma unroll
    for (int j2 = 0; j2 < 4; j2++) {
      const int col = n0 + wn * 64 + j2 * 16 + ll;
#pragma unroll
      for (int r = 0; r < 4; r++) {
        int rr = rowb + r;
        float v = acc[i][j2][r];
        if (RES) v += Rres[(long)rr * N + col];
        if (OM == 1) {
          fout[(long)rr * N + col] = v;
        } else {
          ((u16*)Cout)[(long)rr * N + col] = f2bf(v);
        }
      }
    }
  }
}

// ---------------- 256x256 8-phase GEMM (m201 template) ----------------
// OM: 3 = fused qkv epilogue; 6 = split-K bf16 partial; 7 = interleaved W13+SwiGLU
#define STG_A(d, h, kt)                                                         \
  { gload_lds16(A + aoff[0] + (long)(h) * 128 * Kstr + (kt) * 64, &sA[d][h][dst0]); \
    gload_lds16(A + aoff[1] + (long)(h) * 128 * Kstr + (kt) * 64, &sA[d][h][dst1]); }
#define STG_B(d, h, kt)                                                         \
  { gload_lds16(Bm + boff[0] + (long)(h) * 128 * Kstr + (kt) * 64, &sB[d][h][dst0]); \
    gload_lds16(Bm + boff[1] + (long)(h) * 128 * Kstr + (kt) * 64, &sB[d][h][dst1]); }

#define PHASE(q, d, DOB, WVN, ...)                                              \
  {                                                                             \
    bf16x8 af_[2][2];                                                           \
    _Pragma("unroll") for (int s_ = 0; s_ < 2; s_++)                            \
    _Pragma("unroll") for (int kk_ = 0; kk_ < 2; kk_++) {                       \
      int ms_ = (q) * 4 + wm * 2 + s_;                                          \
      int lo_ = ((ms_ & 7) * 16 + ll) * 128 + kk_ * 64 + lq * 16;               \
      af_[s_][kk_] = *(const bf16x8*)((const char*)sA[d][ms_ >> 3] + swz16(lo_)); \
    }                                                                           \
    if (DOB) {                                                                  \
      _Pragma("unroll") for (int ns_ = 0; ns_ < 4; ns_++)                       \
      _Pragma("unroll") for (int kk_ = 0; kk_ < 2; kk_++) {                     \
        int rl_ = wn * 64 + ns_ * 16 + ll;                                      \
        int lo_ = (rl_ & 127) * 128 + kk_ * 64 + lq * 16;                       \
        bfr[ns_][kk_] = *(const bf16x8*)((const char*)sB[d][rl_ >> 7] + swz16(lo_)); \
      }                                                                         \
    }                                                                           \
    __VA_ARGS__;                                                                \
    __builtin_amdgcn_s_barrier();                                               \
    asm volatile("s_waitcnt lgkmcnt(0)" ::: "memory");                          \
    __builtin_amdgcn_sched_barrier(0);                                          \
    __builtin_amdgcn_s_setprio(1);                                              \
    _Pragma("unroll") for (int s_ = 0; s_ < 2; s_++)                            \
    _Pragma("unroll") for (int ns_ = 0; ns_ < 4; ns_++)                         \
    _Pragma("unroll") for (int kk_ = 0; kk_ < 2; kk_++)                         \
      acc[q][s_][ns_] = __builtin_amdgcn_mfma_f32_16x16x32_bf16(                \
          af_[s_][kk_], bfr[ns_][kk_], acc[q][s_][ns_], 0, 0, 0);               \
    __builtin_amdgcn_s_setprio(0);                                              \
    { int wv_ = (WVN);                                                          \
      if (wv_ == 6) { asm volatile("s_waitcnt vmcnt(6)" ::: "memory"); }        \
      else if (wv_ == 0) { asm volatile("s_waitcnt vmcnt(0)" ::: "memory"); } } \
    __builtin_amdgcn_s_barrier();                                               \
  }

// L2-fit chunk map, sequential chunk-rounds per XCD.
template <int OM, int CW, int CH>
__global__ __launch_bounds__(512) void k_gemm8(const u16* __restrict__ A,
                                               const u16* __restrict__ Bm,
                                               void* __restrict__ Cout,
                                               int N, int Kl, int Kstr) {
  __shared__ u16 sA[2][2][8192];   // [dbuf][half][128*64]
  __shared__ u16 sB[2][2][8192];
  constexpr int NBPC = CW * CH;
  const int gx = gridDim.x;
  const int lin = blockIdx.y * gx + blockIdx.x;
  const int c = lin & 7;
  const int idx = lin >> 3;
  const int chunkid = c + 8 * (idx / NBPC);
  const int jj = idx % NBPC;
  const int ncc = gx / CW;
  const int bx = (chunkid % ncc) * CW + jj % CW;
  const int by = (chunkid / ncc) * CH + jj / CW;
  const long m0 = (long)by * 256, n0 = (long)bx * 256;
  const int tid = threadIdx.x;
  const int wid = tid >> 6, lane = tid & 63;
  const int wm = wid >> 2, wn = wid & 3;
  const int lq = lane >> 4, ll = lane & 15;
  const long zoff = (long)blockIdx.z * Kl;

  long aoff[2], boff[2];
#pragma unroll
  for (int j2 = 0; j2 < 2; j2++) {
    int off = j2 * 8192 + wid * 1024 + lane * 16;
    int lo = swz16(off);
    int r = lo >> 7, cc = (lo & 127) >> 1;
    aoff[j2] = (m0 + r) * Kstr + cc + zoff;
    boff[j2] = (n0 + r) * Kstr + cc + zoff;
  }
  const int dst0 = wid * 512;
  const int dst1 = 4096 + wid * 512;

  f32x4 acc[4][2][4] = {};
  bf16x8 bfr[4][2];

  const int NT = Kl >> 6;
  const int NI = NT >> 1;

  STG_A(0, 0, 0); STG_A(0, 1, 0); STG_B(0, 0, 0); STG_B(0, 1, 0);
  STG_B(1, 0, 1); STG_B(1, 1, 1); STG_A(1, 0, 1);
  asm volatile("s_waitcnt vmcnt(6)" ::: "memory");
  __builtin_amdgcn_s_barrier();

  for (int it = 0; it < NI; it++) {
    const int t = 2 * it;
    const bool full = (t + 2 < NT);
    PHASE(0, 0, true,  -1,            STG_A(1, 1, t + 1))
    PHASE(1, 0, false, -1,            if (full) STG_B(0, 0, t + 2))
    PHASE(2, 0, false, -1,            if (full) STG_B(0, 1, t + 2))
    PHASE(3, 0, false, full ? 6 : 0,  if (full) STG_A(0, 0, t + 2))
    PHASE(0, 1, true,  -1,            if (full) STG_A(0, 1, t + 2))
    PHASE(1, 1, false, -1,            if (full) STG_B(1, 0, t + 3))
    PHASE(2, 1, false, -1,            if (full) STG_B(1, 1, t + 3))
    PHASE(3, 1, false, full ? 6 : -1, if (full) STG_A(1, 0, t + 3))
  }

#pragma unroll
  for (int q = 0; q < 4; q++)
#pragma unroll
    for (int s = 0; s < 2; s++) {
      const long row0 = m0 + (q * 4 + wm * 2 + s) * 16 + lq * 4;
      if (OM == 7) {
        // interleaved SwiGLU: ns even = x1, ns odd = x3, same out col
#pragma unroll
        for (int n2 = 0; n2 < 2; n2++) {
          const long ocol = ((n0 + wn * 64) >> 1) + n2 * 16 + ll;
#pragma unroll
          for (int r = 0; r < 4; r++) {
            float v1 = acc[q][s][n2 * 2][r];
            float v3 = acc[q][s][n2 * 2 + 1][r];
            float g = v1 / (1.0f + __expf(-v1)) * v3;
            ((u16*)Cout)[(row0 + r) * 4096 + ocol] = f2bf(g);
          }
        }
      } else {
#pragma unroll
        for (int ns = 0; ns < 4; ns++) {
          const long col = n0 + wn * 64 + ns * 16 + ll;
#pragma unroll
          for (int r = 0; r < 4; r++) {
            float v = acc[q][s][ns][r];
            long rr = row0 + r;
            if (OM == 3) {
              if (col < 2048) {
                ((u16*)Cout)[(col >> 10) * (long)(Mm * 1024) + rr * 1024 + (col & 1023)] = f2bf(v);
              } else {
                int d = col & 63, hh = ((int)col >> 6) & 15;
                int b2 = (int)rr >> 11, s2 = (int)rr & (Ss - 1);
                ((u16*)Cout)[(long)(2 * Mm * 1024) + ((long)((b2 * Hh + hh) * DKk + d)) * Ss + s2] = f2bf(v);
              }
            } else { // OM == 6: bf16 partial at z-slice offset
              ((u16*)Cout)[(long)blockIdx.z * Mm * (long)N + rr * N + col] = f2bf(v);
            }
          }
        }
      }
    }
}

// ---------------- flash attention, paired q-tiles, KVBLK=64, XCD-affinity ----------------
constexpr int PPAD = 80;

DEV void attn_tile(const u16* __restrict__ Kc, const u16* __restrict__ Vc,
                   u16* __restrict__ myP, const bf16x8* qf, f32x4* accO,
                   float* mrow, float* lrow, int qloc, bool diag, int lq, int ll) {
  f32x4 sacc[4] = {};
  __builtin_amdgcn_s_setprio(1);
#pragma unroll
  for (int fn = 0; fn < 4; fn++)
#pragma unroll
    for (int ks = 0; ks < 2; ks++) {
      bf16x8 kf = *(const bf16x8*)&Kc[(fn * 16 + ll) * 64 + (((ks * 4 + lq) ^ (ll & 7)) * 8)];
      sacc[fn] = __builtin_amdgcn_mfma_f32_16x16x32_bf16(qf[ks], kf, sacc[fn], 0, 0, 0);
    }
  __builtin_amdgcn_s_setprio(0);
  float sv[4][4], pmax[4];
#pragma unroll
  for (int r = 0; r < 4; r++) pmax[r] = -1e30f;
#pragma unroll
  for (int fn = 0; fn < 4; fn++) {
    int kc = fn * 16 + ll;
#pragma unroll
    for (int r = 0; r < 4; r++) {
      float v = sacc[fn][r];
      if (diag && kc > qloc + r) v = -1e30f;
      sv[fn][r] = v;
      pmax[r] = fmaxf(pmax[r], v);
    }
  }
#pragma unroll
  for (int r = 0; r < 4; r++) {
#pragma unroll
    for (int m = 1; m < 16; m <<= 1) pmax[r] = fmaxf(pmax[r], __shfl_xor(pmax[r], m, 64));
  }
  float alpha[4], rsum[4];
#pragma unroll
  for (int r = 0; r < 4; r++) {
    float mnew = fmaxf(mrow[r], pmax[r]);
    alpha[r] = __expf(mrow[r] - mnew);
    mrow[r] = mnew;
    rsum[r] = 0.f;
  }
#pragma unroll
  for (int fn = 0; fn < 4; fn++) {
#pragma unroll
    for (int r = 0; r < 4; r++) {
      float p = __expf(sv[fn][r] - mrow[r]);
      rsum[r] += p;
      myP[(lq * 4 + r) * PPAD + fn * 16 + ll] = f2bf(p);
    }
  }
#pragma unroll
  for (int r = 0; r < 4; r++) {
#pragma unroll
    for (int m = 1; m < 16; m <<= 1) rsum[r] += __shfl_xor(rsum[r], m, 64);
    lrow[r] = lrow[r] * alpha[r] + rsum[r];
  }
#pragma unroll
  for (int fn = 0; fn < 4; fn++)
#pragma unroll
    for (int r = 0; r < 4; r++) accO[fn][r] *= alpha[r];
  bf16x8 pa[2];
#pragma unroll
  for (int ks = 0; ks < 2; ks++)
    pa[ks] = *(const bf16x8*)&myP[ll * PPAD + ks * 32 + lq * 8];
  __builtin_amdgcn_s_setprio(1);
#pragma unroll
  for (int fn = 0; fn < 4; fn++)
#pragma unroll
    for (int ks = 0; ks < 2; ks++) {
      bf16x8 vf = *(const bf16x8*)&Vc[(fn * 16 + ll) * 64 + (((ks * 4 + lq) ^ (ll & 7)) * 8)];
      accO[fn] = __builtin_amdgcn_mfma_f32_16x16x32_bf16(pa[ks], vf, accO[fn], 0, 0, 0);
    }
  __builtin_amdgcn_s_setprio(0);
}

__global__ __launch_bounds__(256) void k_attn(const u16* __restrict__ Q,
                                              const u16* __restrict__ Kb,
                                              const u16* __restrict__ VT,
                                              u16* __restrict__ O) {
  __shared__ u16 Kt[2][64 * 64];
  __shared__ u16 Vt[2][64 * 64];
  __shared__ u16 P[4][16 * PPAD];
  // XCD-affinity remap: all 16 pair-blocks of one bh land on the same XCD
  // (lin&7 == bh&7), so that head's K/V stays L2-resident. Bijective.
  const int lin = blockIdx.y * 16 + blockIdx.x;   // 0..511
  const int xcd = lin & 7, idx = lin >> 3;        // idx 0..63
  const int bh = xcd + 8 * (idx & 3);             // 4 heads per XCD
  const int pair = idx >> 2;                      // 0..15
  const int b = bh >> 4, h = bh & 15;
  const int tid = threadIdx.x;
  const int wid = tid >> 6, lane = tid & 63;
  const int lq = lane >> 4, ll = lane & 15;
  const int qtA = pair, qtB = 31 - pair;
  const int qr0A = qtA * 64 + wid * 16;
  const int qr0B = qtB * 64 + wid * 16;
  const int qloc = wid * 16 + lq * 4;
  const long qkbase = ((long)b * Ss) * Dd + h * DKk;
  const long vbase  = ((long)(b * Hh + h) * DKk) * Ss;
  const int nk = 32 - pair;

  const int slot0 = wid * 64 + lane;
  const int r0 = slot0 >> 3, c0 = (slot0 & 7) ^ (r0 & 7);
  const int slot1 = 256 + slot0;
  const int r1 = slot1 >> 3, c1 = (slot1 & 7) ^ (r1 & 7);
  const int ldsb0 = (wid * 64) * 8;
  const int ldsb1 = (256 + wid * 64) * 8;

  bf16x8 qfA[2], qfB[2];
#pragma unroll
  for (int ks = 0; ks < 2; ks++) {
    qfA[ks] = *(const bf16x8*)&Q[qkbase + (long)(qr0A + ll) * Dd + ks * 32 + lq * 8];
    qfB[ks] = *(const bf16x8*)&Q[qkbase + (long)(qr0B + ll) * Dd + ks * 32 + lq * 8];
  }

  f32x4 accA[4] = {}, accB[4] = {};
  float mA[4], lA[4], mB[4], lB[4];
#pragma unroll
  for (int r = 0; r < 4; r++) { mA[r] = mB[r] = -1e30f; lA[r] = lB[r] = 0.f; }
  u16* myP = P[wid];

  gload_lds16(Kb + qkbase + (long)r0 * Dd + c0 * 8, Kt[0] + ldsb0);
  gload_lds16(Kb + qkbase + (long)r1 * Dd + c1 * 8, Kt[0] + ldsb1);
  gload_lds16(VT + vbase + (long)r0 * Ss + c0 * 8, Vt[0] + ldsb0);
  gload_lds16(VT + vbase + (long)r1 * Ss + c1 * 8, Vt[0] + ldsb1);
  __syncthreads();

  for (int kt = 0; kt < nk; kt++) {
    if (kt + 1 < nk) {
      const int kn = (kt + 1) * 64;
      u16* kd = Kt[(kt + 1) & 1];
      u16* vd = Vt[(kt + 1) & 1];
      gload_lds16(Kb + qkbase + (long)(kn + r0) * Dd + c0 * 8, kd + ldsb0);
      gload_lds16(Kb + qkbase + (long)(kn + r1) * Dd + c1 * 8, kd + ldsb1);
      gload_lds16(VT + vbase + (long)r0 * Ss + kn + c0 * 8, vd + ldsb0);
      gload_lds16(VT + vbase + (long)r1 * Ss + kn + c1 * 8, vd + ldsb1);
    }
    const u16* Kc = Kt[kt & 1];
    const u16* Vc = Vt[kt & 1];

    attn_tile(Kc, Vc, myP, qfB, accB, mB, lB, qloc, kt == nk - 1, lq, ll);
    if (kt <= pair)
      attn_tile(Kc, Vc, myP, qfA, accA, mA, lA, qloc, kt == pair, lq, ll);
    __syncthreads();
  }

#pragma unroll
  for (int fn = 0; fn < 4; fn++) {
#pragma unroll
    for (int r = 0; r < 4; r++) {
      int rowA = qr0A + lq * 4 + r;
      int rowB = qr0B + lq * 4 + r;
      O[((long)(b * Ss + rowA)) * Dd + h * DKk + fn * 16 + ll] = f2bf(accA[fn][r] / lA[r]);
      O[((long)(b * Ss + rowB)) * Dd + h * DKk + fn * 16 + ll] = f2bf(accB[fn][r] / lB[r]);
    }
  }
}

extern "C" void kernel_launch(void* const* d_in, const int* in_sizes, int n_in,
                              void* d_out, int out_size, void* d_ws, size_t ws_size,
                              hipStream_t stream) {
  const float* x   = (const float*)d_in[0];
  const int*   tp  = (const int*)d_in[1];
  const float* wq  = (const float*)d_in[2];
  const float* wk  = (const float*)d_in[3];
  const float* wv  = (const float*)d_in[4];
  const float* wo  = (const float*)d_in[5];
  const float* ln1 = (const float*)d_in[6];
  const float* ln2 = (const float*)d_in[7];
  const float* w1  = (const float*)d_in[8];
  const float* w2  = (const float*)d_in[9];
  const float* w3  = (const float*)d_in[10];

  char* ws = (char*)d_ws;
  const size_t MB = 1024 * 1024;
  u16*   wqkv_b = (u16*)(ws + 0 * MB);
  u16*   wo_b   = (u16*)(ws + 6 * MB);
  u16*   w13_b  = (u16*)(ws + 8 * MB);    // interleaved w1/w3, 16MB
  u16*   w2_b   = (u16*)(ws + 24 * MB);
  u16*   xn     = (u16*)(ws + 32 * MB);
  float* x2     = (float*)(ws + 40 * MB);
  u16*   qb     = (u16*)(ws + 56 * MB);
  u16*   kb     = (u16*)(ws + 64 * MB);
  u16*   vtb    = (u16*)(ws + 72 * MB);
  u16*   ob     = (u16*)(ws + 80 * MB);
  u16*   x1     = (u16*)(ws + 56 * MB);   // gated [4096][4096] (overlays q/k/vt)
  u16*   pparts = (u16*)(ws + 88 * MB);   // 4 x 8MB bf16 partials

  // weights->bf16 (w1/w3 interleaved) + ln1
  k_prep<<<16384 + Mm, 256, 0, stream>>>(wq, wk, wv, wo, w1, w2, w3,
                                         wqkv_b, wo_b, w13_b, w2_b, x, ln1, xn);
  // QKV: chunks 3x4 tiles
  k_gemm8<3, 3, 4><<<dim3(12, 16), 512, 0, stream>>>(xn, wqkv_b, qb, 3072, 1024, 1024);
  k_rope<<<(Bb * Ss * Hh * 32) / 256, 256, 0, stream>>>(qb, kb, tp);
  k_attn<<<dim3(16, 32), 256, 0, stream>>>(qb, kb, vtb, ob);
  k_gemm<1, true><<<dim3(8, 32), 256, 0, stream>>>(ob, wo_b, x2, x, 1024, 1024, 1024);
  k_rmsnorm<<<Mm, 256, 0, stream>>>(x2, ln2, xn);
  // W13 + in-epilogue SwiGLU -> gated x1 [4096][4096]
  k_gemm8<7, 4, 4><<<dim3(32, 16), 512, 0, stream>>>(xn, w13_b, x1, 8192, 1024, 1024);
  // W2: 8-phase split-K x4, bf16 partials -> combine
  k_gemm8<6, 4, 2><<<dim3(4, 16, 4), 512, 0, stream>>>(x1, w2_b, pparts, 1024, 1024, 4096);
  k_addout4<<<4096, 256, 0, stream>>>(pparts, x2, (float*)d_out);
}